// Round 1
// baseline (389.577 us; speedup 1.0000x reference)
//
#include <hip/hip_runtime.h>
#include <hip/hip_bf16.h>
#include <float.h>

// Problem constants
#define BB    2
#define NSEQ  2048
#define CDIM  1024
#define HH    16
#define DD    64
#define KKEEP 1228
#define KP    1280   // KKEEP padded to multiple of 64

typedef __attribute__((ext_vector_type(8))) short short8_t;
typedef __attribute__((ext_vector_type(4))) short short4_t;
typedef __attribute__((ext_vector_type(4))) int   int4_t;
typedef __attribute__((ext_vector_type(4))) float f32x4;
typedef __attribute__((ext_vector_type(4))) float float4_t;
typedef __bf16 bf16x8 __attribute__((ext_vector_type(8)));

static __device__ __forceinline__ short f2bf(float x) {
  __hip_bfloat16 h = __float2bfloat16(x);
  short s;
  __builtin_memcpy(&s, &h, 2);
  return s;
}

static __device__ __forceinline__ f32x4 mfma16(bf16x8 a, bf16x8 b, f32x4 c) {
  return __builtin_amdgcn_mfma_f32_16x16x32_bf16(a, b, c, 0, 0, 0);
}

// ---------------- cast kernels ----------------
__global__ __launch_bounds__(256) void cast_f32_bf16_kernel(
    const float* __restrict__ src, short* __restrict__ dst, int n4) {
  int i = blockIdx.x * 256 + threadIdx.x;
  if (i >= n4) return;
  float4_t v = ((const float4_t*)src)[i];
  short4_t o;
  o[0] = f2bf(v[0]); o[1] = f2bf(v[1]); o[2] = f2bf(v[2]); o[3] = f2bf(v[3]);
  ((short4_t*)dst)[i] = o;
}

// Permute W_qkv rows: dst row rr = c*1024 + h*64 + d  <-  src row h*192 + d*3 + c
__global__ __launch_bounds__(256) void cast_wqkv_kernel(
    const float* __restrict__ w, short* __restrict__ dst) {
  int rr = blockIdx.x;              // 0..3071
  int c = rr >> 10, hd = rr & 1023;
  int h = hd >> 6, d = hd & 63;
  int srow = h * 192 + d * 3 + c;
  int col = threadIdx.x * 4;
  float4_t v = *(const float4_t*)(w + (size_t)srow * CDIM + col);
  short4_t o;
  o[0] = f2bf(v[0]); o[1] = f2bf(v[1]); o[2] = f2bf(v[2]); o[3] = f2bf(v[3]);
  *(short4_t*)(dst + (size_t)rr * CDIM + col) = o;
}

// ---------------- GEMM: C[M,N] = A[M,K] * B[N,K]^T (both bf16, fp32 acc) ----------------
// EPI==0: scatter to q/k/v [B,H,N,D] bf16 (col = c*1024 + h*64 + d)
// EPI==1: write fp32 to outF [M,N]
template <int EPI>
__global__ __launch_bounds__(256) void gemm_bt_kernel(
    const short* __restrict__ A, const short* __restrict__ B, int K, int N,
    float* __restrict__ outF, short* __restrict__ outQ,
    short* __restrict__ outK, short* __restrict__ outV) {
  __shared__ short lA[128 * 32];
  __shared__ short lB[128 * 32];
  int m0 = blockIdx.y * 128, n0 = blockIdx.x * 128;
  int tid = threadIdx.x, lane = tid & 63;
  int w = tid >> 6;
  int lq = lane & 15, lg = lane >> 4;
  int wm = w >> 1, wn = w & 1;

  f32x4 acc[4][4];
#pragma unroll
  for (int m = 0; m < 4; ++m)
#pragma unroll
    for (int n = 0; n < 4; ++n) acc[m][n] = (f32x4){0.f, 0.f, 0.f, 0.f};

  const int c0 = tid, c1 = tid + 256;
  for (int k0 = 0; k0 < K; k0 += 32) {
    short8_t a0 = *(const short8_t*)(A + (size_t)(m0 + (c0 >> 2)) * K + k0 + (c0 & 3) * 8);
    short8_t a1 = *(const short8_t*)(A + (size_t)(m0 + (c1 >> 2)) * K + k0 + (c1 & 3) * 8);
    short8_t b0 = *(const short8_t*)(B + (size_t)(n0 + (c0 >> 2)) * K + k0 + (c0 & 3) * 8);
    short8_t b1 = *(const short8_t*)(B + (size_t)(n0 + (c1 >> 2)) * K + k0 + (c1 & 3) * 8);
    *(short8_t*)(lA + c0 * 8) = a0;
    *(short8_t*)(lA + c1 * 8) = a1;
    *(short8_t*)(lB + c0 * 8) = b0;
    *(short8_t*)(lB + c1 * 8) = b1;
    __syncthreads();
    bf16x8 af[4], bf[4];
#pragma unroll
    for (int m = 0; m < 4; ++m)
      af[m] = *(const bf16x8*)(lA + (wm * 64 + m * 16 + lq) * 32 + lg * 8);
#pragma unroll
    for (int n = 0; n < 4; ++n)
      bf[n] = *(const bf16x8*)(lB + (wn * 64 + n * 16 + lq) * 32 + lg * 8);
#pragma unroll
    for (int m = 0; m < 4; ++m)
#pragma unroll
      for (int n = 0; n < 4; ++n) acc[m][n] = mfma16(af[m], bf[n], acc[m][n]);
    __syncthreads();
  }

#pragma unroll
  for (int m = 0; m < 4; ++m)
#pragma unroll
    for (int n = 0; n < 4; ++n) {
      int row_b = m0 + wm * 64 + m * 16 + lg * 4;
      int col = n0 + wn * 64 + n * 16 + lq;
#pragma unroll
      for (int r = 0; r < 4; ++r) {
        float v = acc[m][n][r];
        int row = row_b + r;
        if constexpr (EPI == 1) {
          outF[(size_t)row * N + col] = v;
        } else {
          int c = col >> 10, cc = col & 1023;
          short* dst = (c == 0) ? outQ : (c == 1) ? outK : outV;
          dst[((size_t)((row >> 11) * HH + (cc >> 6)) * NSEQ + (row & 2047)) * DD + (cc & 63)] =
              f2bf(v);
        }
      }
    }
}

// ---------------- top-k selection (stable: value desc, index asc) ----------------
__global__ __launch_bounds__(256) void topk_kernel(const int* __restrict__ seq_mask,
                                                   int* __restrict__ idx_out) {
  __shared__ int hist[10];
  __shared__ int vals[NSEQ];
  __shared__ int sgt[256], seqc[256];
  __shared__ int sT, sNeed;
  int bh = blockIdx.x, tid = threadIdx.x;
  if (tid < 10) hist[tid] = 0;
  __syncthreads();
  const int* sm = seq_mask + (size_t)bh * NSEQ;
  for (int i = tid; i < NSEQ; i += 256) {
    int v = sm[i];
    vals[i] = v;
    atomicAdd(&hist[v], 1);
  }
  __syncthreads();
  if (tid == 0) {
    int cum = 0, t = 0;
    for (int v = 9; v >= 0; --v) {
      int hv = hist[v];
      if (cum + hv >= KKEEP) { t = v; break; }
      cum += hv;
    }
    sT = t;
    sNeed = KKEEP - cum;   // how many ties (value==t) to keep, lowest indices first
  }
  __syncthreads();
  int t = sT, need = sNeed;
  int base = tid * 8, lgt = 0, leq = 0;
  int lv[8];
#pragma unroll
  for (int j = 0; j < 8; ++j) {
    lv[j] = vals[base + j];
    lgt += (lv[j] > t);
    leq += (lv[j] == t);
  }
  sgt[tid] = lgt;
  seqc[tid] = leq;
  __syncthreads();
  for (int off = 1; off < 256; off <<= 1) {
    int a = 0, b2 = 0;
    if (tid >= off) { a = sgt[tid - off]; b2 = seqc[tid - off]; }
    __syncthreads();
    sgt[tid] += a;
    seqc[tid] += b2;
    __syncthreads();
  }
  int gtp = sgt[tid] - lgt;   // exclusive prefix of (v>t)
  int eqp = seqc[tid] - leq;  // exclusive prefix of (v==t)
  int* op = idx_out + (size_t)bh * KP;
#pragma unroll
  for (int j = 0; j < 8; ++j) {
    int v = lv[j];
    if (v > t) {
      op[gtp + (eqp < need ? eqp : need)] = base + j;
      gtp++;
    } else if (v == t) {
      if (eqp < need) op[gtp + eqp] = base + j;
      eqp++;
    }
  }
  for (int kpos = KKEEP + tid; kpos < KP; kpos += 256) op[kpos] = -1;
}

// ---------------- gather kept K rows (kk[bh][kpos][d]) and V transposed (vvT[bh][d][kpos]) ----
__global__ __launch_bounds__(256) void gather_kernel(
    const short* __restrict__ kb, const short* __restrict__ vb,
    const int* __restrict__ idx, short* __restrict__ kko, short* __restrict__ vvT) {
  __shared__ short vt[64][72];   // 72*2=144B rows (16B-aligned), padded vs bank collisions
  int bh = blockIdx.y, cb = blockIdx.x;
  int tid = threadIdx.x;
  int kbase = cb * 64;
  int rr0 = tid >> 3;
  int d0 = (tid & 7) * 8;
#pragma unroll
  for (int it = 0; it < 2; ++it) {
    int rr = rr0 + it * 32;
    int kpos = kbase + rr;
    int jor = idx[(size_t)bh * KP + kpos];
    short8_t kv = 0, vv = 0;
    if (jor >= 0) {
      kv = *(const short8_t*)(kb + ((size_t)bh * NSEQ + jor) * DD + d0);
      vv = *(const short8_t*)(vb + ((size_t)bh * NSEQ + jor) * DD + d0);
    }
    *(short8_t*)(kko + ((size_t)bh * KP + kpos) * DD + d0) = kv;
    *(short8_t*)&vt[rr][d0] = vv;
  }
  __syncthreads();
  int d = tid >> 2;
  int j0 = (tid & 3) * 16;
  short8_t s0, s1;
#pragma unroll
  for (int j = 0; j < 8; ++j) s0[j] = vt[j0 + j][d];
#pragma unroll
  for (int j = 0; j < 8; ++j) s1[j] = vt[j0 + 8 + j][d];
  short* obase = vvT + ((size_t)bh * DD + d) * KP + kbase + j0;
  *(short8_t*)obase = s0;
  *(short8_t*)(obase + 8) = s1;
}

// ---------------- flash attention over compacted keys ----------------
// grid (N/64, B*H); 4 waves/block, each wave owns 16 query rows.
// S^T = mfma(K, Q): lane holds query q=lane&15, keys (lane>>4)*4+r.
__global__ __launch_bounds__(256) void attn_kernel(
    const short* __restrict__ qb, const short* __restrict__ kk,
    const short* __restrict__ vvT, const int* __restrict__ idx,
    const float* __restrict__ pos_bias, short* __restrict__ attn_out) {
  __shared__ short pls[4][16][32];   // per-wave P bounce (q x key32), bf16
  int bh = blockIdx.y;
  int h = bh & (HH - 1), b = bh >> 4;
  int w = threadIdx.x >> 6, lane = threadIdx.x & 63;
  int lq = lane & 15, lg = lane >> 4;
  int q0 = blockIdx.x * 64 + w * 16;
  int qglob = q0 + lq;

  const short* qp = qb + ((size_t)bh * NSEQ + qglob) * DD;
  bf16x8 qf0 = *(const bf16x8*)(qp + lg * 8);
  bf16x8 qf1 = *(const bf16x8*)(qp + 32 + lg * 8);

  const float* pbrow = pos_bias + ((size_t)h * NSEQ + qglob) * NSEQ;
  const int* idxp = idx + (size_t)bh * KP;

  float mrun = -FLT_MAX, lsum = 0.f;
  f32x4 o0 = (f32x4){0.f,0.f,0.f,0.f}, o1 = o0, o2 = o0, o3 = o0;

  for (int kb0 = 0; kb0 < KP; kb0 += 32) {
    float sv[8];
    int vbits = 0;
    float cm = -FLT_MAX;
#pragma unroll
    for (int c = 0; c < 2; ++c) {
      int kbase = kb0 + c * 16;
      const short* kp = kk + ((size_t)bh * KP + kbase + lq) * DD + lg * 8;
      bf16x8 ak0 = *(const bf16x8*)kp;
      bf16x8 ak1 = *(const bf16x8*)(kp + 32);
      f32x4 s = (f32x4){0.f,0.f,0.f,0.f};
      s = mfma16(ak0, qf0, s);
      s = mfma16(ak1, qf1, s);
      int4_t j4 = *(const int4_t*)(idxp + kbase + lg * 4);
#pragma unroll
      for (int r = 0; r < 4; ++r) {
        int jor = j4[r];
        float x;
        if (jor >= 0 && jor <= qglob) {
          x = s[r] * 0.125f + pbrow[jor];
        } else {
          x = -FLT_MAX;   // causal-masked (jor>qglob) or pad (jor<0)
        }
        if (jor >= 0) vbits |= (1 << (c * 4 + r));
        sv[c * 4 + r] = x;
        cm = fmaxf(cm, x);
      }
    }
    cm = fmaxf(cm, __shfl_xor(cm, 16));
    cm = fmaxf(cm, __shfl_xor(cm, 32));
    float mnew = fmaxf(mrun, cm);
    float f = __expf(mrun - mnew);   // ==1 when both -FLT_MAX (uniform case)
    float psum = 0.f;
    short pb16[8];
#pragma unroll
    for (int j2 = 0; j2 < 8; ++j2) {
      float pv = ((vbits >> j2) & 1) ? __expf(sv[j2] - mnew) : 0.f;
      psum += pv;
      pb16[j2] = f2bf(pv);
    }
    lsum = lsum * f + psum;
    mrun = mnew;

    // bounce P to LDS (wave-local, DS ops in-order per wave -> no barrier)
    short4_t w0 = {pb16[0], pb16[1], pb16[2], pb16[3]};
    short4_t w1 = {pb16[4], pb16[5], pb16[6], pb16[7]};
    *(short4_t*)&pls[w][lq][lg * 4] = w0;
    *(short4_t*)&pls[w][lq][16 + lg * 4] = w1;
    bf16x8 pa = *(const bf16x8*)&pls[w][lq][lg * 8];

    // rescale running O (rows q = lg*4+r)
    float f0 = __shfl(f, lg * 4 + 0);
    float f1 = __shfl(f, lg * 4 + 1);
    float f2 = __shfl(f, lg * 4 + 2);
    float f3 = __shfl(f, lg * 4 + 3);
    o0[0] *= f0; o0[1] *= f1; o0[2] *= f2; o0[3] *= f3;
    o1[0] *= f0; o1[1] *= f1; o1[2] *= f2; o1[3] *= f3;
    o2[0] *= f0; o2[1] *= f1; o2[2] *= f2; o2[3] *= f3;
    o3[0] *= f0; o3[1] *= f1; o3[2] *= f2; o3[3] *= f3;

    const short* vp = vvT + ((size_t)bh * DD + lq) * KP + kb0 + lg * 8;
    o0 = mfma16(pa, *(const bf16x8*)(vp + (size_t)0 * 16 * KP), o0);
    o1 = mfma16(pa, *(const bf16x8*)(vp + (size_t)1 * 16 * KP), o1);
    o2 = mfma16(pa, *(const bf16x8*)(vp + (size_t)2 * 16 * KP), o2);
    o3 = mfma16(pa, *(const bf16x8*)(vp + (size_t)3 * 16 * KP), o3);
  }

  float ltot = lsum;
  ltot += __shfl_xor(ltot, 16);
  ltot += __shfl_xor(ltot, 32);
  float inv = 1.f / ltot;
  float i0 = __shfl(inv, lg * 4 + 0);
  float i1 = __shfl(inv, lg * 4 + 1);
  float i2 = __shfl(inv, lg * 4 + 2);
  float i3 = __shfl(inv, lg * 4 + 3);

  short* ob = attn_out + ((size_t)b * NSEQ + q0 + lg * 4) * CDIM + h * DD + lq;
#pragma unroll
  for (int r = 0; r < 4; ++r) {
    float ir = (r == 0) ? i0 : (r == 1) ? i1 : (r == 2) ? i2 : i3;
    short* orow = ob + (size_t)r * CDIM;
    orow[0]  = f2bf(o0[r] * ir);
    orow[16] = f2bf(o1[r] * ir);
    orow[32] = f2bf(o2[r] * ir);
    orow[48] = f2bf(o3[r] * ir);
  }
}

// ---------------- launch ----------------
extern "C" void kernel_launch(void* const* d_in, const int* in_sizes, int n_in,
                              void* d_out, int out_size, void* d_ws, size_t ws_size,
                              hipStream_t stream) {
  const float* x        = (const float*)d_in[0];
  const float* Wqkv     = (const float*)d_in[1];
  const float* Wout     = (const float*)d_in[2];
  const float* pos_bias = (const float*)d_in[3];
  const int*   seq_mask = (const int*)d_in[4];
  float* out = (float*)d_out;

  char* ws = (char*)d_ws;
  short* xb    = (short*)(ws);                          // 8 MB  x bf16 [4096,1024]
  short* wqkvb = (short*)(ws + ((size_t)8  << 20));     // 6 MB  permuted W_qkv bf16 [3072,1024]
  short* woutb = (short*)(ws + ((size_t)14 << 20));     // 2 MB  W_out bf16 [1024,1024]
  short* qb    = (short*)(ws + ((size_t)16 << 20));     // 8 MB  q bf16 [B,H,N,D]
  short* kbuf  = (short*)(ws + ((size_t)24 << 20));     // 8 MB  k bf16 [B,H,N,D]
  short* vbuf  = (short*)(ws + ((size_t)32 << 20));     // 8 MB  v bf16 [B,H,N,D]
  int*   idxb  = (int*)  (ws + ((size_t)40 << 20));     // 160 KB idx [BH,KP]
  short* kkb   = (short*)(ws + ((size_t)41 << 20));     // 5 MB  kk bf16 [BH,KP,D]
  short* vvTb  = (short*)(ws + ((size_t)47 << 20));     // 5 MB  vvT bf16 [BH,D,KP]
  short* aob   = (short*)(ws + ((size_t)53 << 20));     // 8 MB  attn_out bf16 [4096,1024]

  cast_f32_bf16_kernel<<<4096, 256, 0, stream>>>(x, xb, (BB * NSEQ * CDIM) / 4);
  cast_wqkv_kernel<<<3072, 256, 0, stream>>>(Wqkv, wqkvb);
  cast_f32_bf16_kernel<<<1024, 256, 0, stream>>>(Wout, woutb, (CDIM * HH * DD) / 4);

  gemm_bt_kernel<0><<<dim3(24, 32), 256, 0, stream>>>(xb, wqkvb, CDIM, 3 * HH * DD,
                                                      nullptr, qb, kbuf, vbuf);

  topk_kernel<<<BB * HH, 256, 0, stream>>>(seq_mask, idxb);
  gather_kernel<<<dim3(KP / 64, BB * HH), 256, 0, stream>>>(kbuf, vbuf, idxb, kkb, vvTb);

  attn_kernel<<<dim3(NSEQ / 64, BB * HH), 256, 0, stream>>>(qb, kkb, vvTb, idxb,
                                                            pos_bias, aob);

  gemm_bt_kernel<1><<<dim3(8, 32), 256, 0, stream>>>(aob, woutb, HH * DD, CDIM,
                                                     out, nullptr, nullptr, nullptr);
}